// Round 12
// baseline (113.022 us; speedup 1.0000x reference)
//
#include <hip/hip_runtime.h>

// GTCNN — 2-kernel fused-layer structure (round 12).
// r4/r9/r10 all ≈33us with wildly different inner loops => per-kernel wall is
// launch/ramp-dominated (~6us overhead per kernel, r8: VALUBusy 8%). Only
// remaining lever: fewer kernels. Each layer fuses into ONE kernel by having
// block (b,t) stream the full 1MB batch slab from L2 (temporal mix for its own
// t — no FLOP duplication), then spatial+filter locally. Layer-0 folds the
// input projection via linearity: T(xW1+b1) = (Tx)W1 + rowsum(At[t])*b1.
//
// Math (verified r2-r11): per layer h' = tanh(P(h) @ Hsum[l]),
//   P(h) = s0 h + s1 S h + s2 T h + s3 S T h  (S = As over n, T = At over t)
//   computed as: mix = T h (streamed); up = s1 h_t + s3 mix; pp = s0 h_t + s2 mix
//                Ah = pp + S up;  h' = tanh(Ah @ Hsum)
// K1 (FIRST): src = x, mixes x then projects (xmix LDS transpose), writes h1.
// K2 (!FIRST): src = h1 (t-major), no projection, fuses out-proj, writes out.
//
// Thread map (512 thr): wave w = tid>>6 -> f-chunk w*4..+4; lane l -> rows
// {l, 64+l} for n (temporal/up/pp) and m (spatial/filter/output).
// up/pp live in registers; spatial reads them cross-lane via readlane (lane
// n&63 holds up[n]) — no LDS round-trip. Lane-distinct LDS tiles use the
// proven XOR group swizzle g' = g ^ (row&7). Broadcast weights = readlane
// slices (lane k holds W1[k][chunk] etc).

#define SWZg(r, g) ((g) ^ ((r) & 7))

__device__ __forceinline__ float rlane(float v, int lane) {
    return __builtin_bit_cast(float, __builtin_amdgcn_readlane(__builtin_bit_cast(int, v), lane));
}

template<bool FIRST>
__global__ __launch_bounds__(512) void k_layer(
    const float* __restrict__ src,   // FIRST ? x : h1   ([B][64][128][32])
    const float* __restrict__ At, const float* __restrict__ As,
    const float* __restrict__ s,  const float* __restrict__ H,
    const float* __restrict__ W1, const float* __restrict__ b1,
    const float* __restrict__ W2, const float* __restrict__ b2,
    float* __restrict__ h1, float* __restrict__ out)
{
    __shared__ float As_s[128 * 128];  // 64KB swizzled
    __shared__ float xm_s[128 * 32];   // 16KB swizzled (FIRST: xmix transpose)
    __shared__ float Ah_s[128 * 32];   // 16KB swizzled
    __shared__ float T_s [128 * 32];   // 16KB swizzled (!FIRST: out-proj)

    const int tid = threadIdx.x;
    const int b   = blockIdx.x >> 6;
    const int t   = blockIdx.x & 63;
    const int w   = tid >> 6;
    const int l   = tid & 63;
    const int w4  = w * 4;

    const float s0v = s[0], s1v = s[1], s2v = s[2], s3v = s[3];

    // ---- stage As [128][128] swizzled (consumed after first sync) ----
#pragma unroll
    for (int i = 0; i < 8; ++i) {
        int p = tid + 512 * i;
        int r = p >> 5, g = p & 31;
        float4 v = *(const float4*)(As + r * 128 + g * 4);
        *(float4*)&As_s[r * 128 + SWZg(r, g) * 4] = v;
    }

    // ---- register slices ----
    float atr = At[t * 64 + l];                       // lane l: At[t][l]
    float4 hsr;                                        // lane l: Hsum[k=l&31][w-chunk]
    {
        const float* Hl = H + (FIRST ? 0 : 4096) + (l & 31) * 32 + w4;
        float4 q0 = *(const float4*)(Hl);
        float4 q1 = *(const float4*)(Hl + 1024);
        float4 q2 = *(const float4*)(Hl + 2048);
        float4 q3 = *(const float4*)(Hl + 3072);
        hsr.x = q0.x + q1.x + q2.x + q3.x;  hsr.y = q0.y + q1.y + q2.y + q3.y;
        hsr.z = q0.z + q1.z + q2.z + q3.z;  hsr.w = q0.w + q1.w + q2.w + q3.w;
    }
    float4 w1r, b1v; float2 w2r, b2v;
    if (FIRST) {
        w1r = *(const float4*)(W1 + (l & 31) * 32 + w4);   // lane k: W1[k][w-chunk]
        b1v = *(const float4*)(b1 + w4);
    } else {
        w2r = *(const float2*)(W2 + (l & 31) * 16 + w * 2); // lane k: W2[k][2fo]
        b2v = *(const float2*)(b2 + w * 2);
    }

    // ---- stream slab: mix[n][w-chunk] = sum_u At[t,u] * src[b][u][n][w-chunk]
    const float* xb = src + (size_t)b * 262144;
    float m00 = 0.f, m01 = 0.f, m02 = 0.f, m03 = 0.f;   // n0 = l
    float m10 = 0.f, m11 = 0.f, m12 = 0.f, m13 = 0.f;   // n1 = 64+l
    float rs = 0.f;                                      // rowsum At[t] (FIRST)
#pragma unroll 8
    for (int u = 0; u < 64; ++u) {
        const float* pu = xb + u * 4096 + w4;
        float4 v0 = *(const float4*)(pu + l * 32);
        float4 v1 = *(const float4*)(pu + (64 + l) * 32);
        float a = rlane(atr, u);
        if (FIRST) rs += a;
        m00 += a * v0.x; m01 += a * v0.y; m02 += a * v0.z; m03 += a * v0.w;
        m10 += a * v1.x; m11 += a * v1.y; m12 += a * v1.z; m13 += a * v1.w;
    }

    // ---- up/pp in registers (lane l holds n = l and n = 64+l) ----
    float4 up0, up1, pp0, pp1;
    if (FIRST) {
        // transpose xmix through LDS to reduce over k
        { float4 t4; t4.x = m00; t4.y = m01; t4.z = m02; t4.w = m03;
          *(float4*)&xm_s[l * 32 + SWZg(l, w) * 4] = t4; }
        { float4 t4; t4.x = m10; t4.y = m11; t4.z = m12; t4.w = m13;
          *(float4*)&xm_s[(64 + l) * 32 + SWZg(64 + l, w) * 4] = t4; }
        __syncthreads();
        // h_t = x[t] @ W1 + b1 ; wm = xmix @ W1 + rs*b1   (readlane W1)
        float h00 = b1v.x, h01 = b1v.y, h02 = b1v.z, h03 = b1v.w;
        float h10 = b1v.x, h11 = b1v.y, h12 = b1v.z, h13 = b1v.w;
        float q00 = rs * b1v.x, q01 = rs * b1v.y, q02 = rs * b1v.z, q03 = rs * b1v.w;
        float q10 = q00, q11 = q01, q12 = q02, q13 = q03;
        const float* xt = xb + t * 4096;
#pragma unroll
        for (int k4 = 0; k4 < 8; ++k4) {
            float4 x0 = *(const float4*)(xt + l * 32 + k4 * 4);          // L2-hot
            float4 x1 = *(const float4*)(xt + (64 + l) * 32 + k4 * 4);
            float4 g0 = *(const float4*)&xm_s[l * 32 + SWZg(l, k4) * 4];
            float4 g1 = *(const float4*)&xm_s[(64 + l) * 32 + SWZg(64 + l, k4) * 4];
#define PRJ(j, XC0, XC1, GC0, GC1)                                      \
            { int k = k4 * 4 + (j);                                     \
              float c0 = rlane(w1r.x, k), c1 = rlane(w1r.y, k);         \
              float c2 = rlane(w1r.z, k), c3 = rlane(w1r.w, k);         \
              h00 += (XC0) * c0; h01 += (XC0) * c1; h02 += (XC0) * c2; h03 += (XC0) * c3; \
              h10 += (XC1) * c0; h11 += (XC1) * c1; h12 += (XC1) * c2; h13 += (XC1) * c3; \
              q00 += (GC0) * c0; q01 += (GC0) * c1; q02 += (GC0) * c2; q03 += (GC0) * c3; \
              q10 += (GC1) * c0; q11 += (GC1) * c1; q12 += (GC1) * c2; q13 += (GC1) * c3; }
            PRJ(0, x0.x, x1.x, g0.x, g1.x)
            PRJ(1, x0.y, x1.y, g0.y, g1.y)
            PRJ(2, x0.z, x1.z, g0.z, g1.z)
            PRJ(3, x0.w, x1.w, g0.w, g1.w)
#undef PRJ
        }
        up0.x = s1v*h00 + s3v*q00; up0.y = s1v*h01 + s3v*q01;
        up0.z = s1v*h02 + s3v*q02; up0.w = s1v*h03 + s3v*q03;
        up1.x = s1v*h10 + s3v*q10; up1.y = s1v*h11 + s3v*q11;
        up1.z = s1v*h12 + s3v*q12; up1.w = s1v*h13 + s3v*q13;
        pp0.x = s0v*h00 + s2v*q00; pp0.y = s0v*h01 + s2v*q01;
        pp0.z = s0v*h02 + s2v*q02; pp0.w = s0v*h03 + s2v*q03;
        pp1.x = s0v*h10 + s2v*q10; pp1.y = s0v*h11 + s2v*q11;
        pp1.z = s0v*h12 + s2v*q12; pp1.w = s0v*h13 + s2v*q13;
    } else {
        // no projection: h_t rows straight from slab (L2-hot re-read)
        float4 hv0 = *(const float4*)(xb + t * 4096 + l * 32 + w4);
        float4 hv1 = *(const float4*)(xb + t * 4096 + (64 + l) * 32 + w4);
        up0.x = s1v*hv0.x + s3v*m00; up0.y = s1v*hv0.y + s3v*m01;
        up0.z = s1v*hv0.z + s3v*m02; up0.w = s1v*hv0.w + s3v*m03;
        up1.x = s1v*hv1.x + s3v*m10; up1.y = s1v*hv1.y + s3v*m11;
        up1.z = s1v*hv1.z + s3v*m12; up1.w = s1v*hv1.w + s3v*m13;
        pp0.x = s0v*hv0.x + s2v*m00; pp0.y = s0v*hv0.y + s2v*m01;
        pp0.z = s0v*hv0.z + s2v*m02; pp0.w = s0v*hv0.w + s2v*m03;
        pp1.x = s0v*hv1.x + s2v*m10; pp1.y = s0v*hv1.y + s2v*m11;
        pp1.z = s0v*hv1.z + s2v*m12; pp1.w = s0v*hv1.w + s2v*m13;
        __syncthreads();                          // As_s ready
    }

    // ---- spatial: Ah[m] = pp[m] + sum_n As[m,n] up[n]  (readlane up) ----
    float4 ac0 = pp0, ac1 = pp1;                  // m0 = l, m1 = 64+l
#pragma unroll
    for (int n4 = 0; n4 < 32; ++n4) {
        float4 a0 = *(const float4*)&As_s[l * 128 + SWZg(l, n4) * 4];
        float4 a1 = *(const float4*)&As_s[(64 + l) * 128 + SWZg(64 + l, n4) * 4];
        const int ln = 4 * (n4 & 15);
#define SPJ(j, AC0, AC1)                                                \
        { float ux, uy, uz, uw;                                         \
          if (n4 < 16) { ux = rlane(up0.x, ln + (j)); uy = rlane(up0.y, ln + (j)); \
                         uz = rlane(up0.z, ln + (j)); uw = rlane(up0.w, ln + (j)); } \
          else        { ux = rlane(up1.x, ln + (j)); uy = rlane(up1.y, ln + (j)); \
                         uz = rlane(up1.z, ln + (j)); uw = rlane(up1.w, ln + (j)); } \
          ac0.x += (AC0) * ux; ac0.y += (AC0) * uy; ac0.z += (AC0) * uz; ac0.w += (AC0) * uw; \
          ac1.x += (AC1) * ux; ac1.y += (AC1) * uy; ac1.z += (AC1) * uz; ac1.w += (AC1) * uw; }
        SPJ(0, a0.x, a1.x)
        SPJ(1, a0.y, a1.y)
        SPJ(2, a0.z, a1.z)
        SPJ(3, a0.w, a1.w)
#undef SPJ
    }
    *(float4*)&Ah_s[l * 32 + SWZg(l, w) * 4] = ac0;
    *(float4*)&Ah_s[(64 + l) * 32 + SWZg(64 + l, w) * 4] = ac1;
    __syncthreads();

    // ---- filter: c[m] = Ah[m] @ Hsum  (readlane Hsum), tanh ----
    float c00 = 0.f, c01 = 0.f, c02 = 0.f, c03 = 0.f;
    float c10 = 0.f, c11 = 0.f, c12 = 0.f, c13 = 0.f;
#pragma unroll
    for (int k4 = 0; k4 < 8; ++k4) {
        float4 v0 = *(const float4*)&Ah_s[l * 32 + SWZg(l, k4) * 4];
        float4 v1 = *(const float4*)&Ah_s[(64 + l) * 32 + SWZg(64 + l, k4) * 4];
#define FLT(j, VC0, VC1)                                                \
        { int k = k4 * 4 + (j);                                         \
          float d0 = rlane(hsr.x, k), d1 = rlane(hsr.y, k);             \
          float d2 = rlane(hsr.z, k), d3 = rlane(hsr.w, k);             \
          c00 += (VC0) * d0; c01 += (VC0) * d1; c02 += (VC0) * d2; c03 += (VC0) * d3; \
          c10 += (VC1) * d0; c11 += (VC1) * d1; c12 += (VC1) * d2; c13 += (VC1) * d3; }
        FLT(0, v0.x, v1.x)
        FLT(1, v0.y, v1.y)
        FLT(2, v0.z, v1.z)
        FLT(3, v0.w, v1.w)
#undef FLT
    }
    c00 = tanhf(c00); c01 = tanhf(c01); c02 = tanhf(c02); c03 = tanhf(c03);
    c10 = tanhf(c10); c11 = tanhf(c11); c12 = tanhf(c12); c13 = tanhf(c13);

    if (FIRST) {
        // write h1 (t-major, contiguous rows for K2's stream)
        float* hb = h1 + ((size_t)(b * 64 + t)) * 4096;
        float4 o0; o0.x = c00; o0.y = c01; o0.z = c02; o0.w = c03;
        float4 o1; o1.x = c10; o1.y = c11; o1.z = c12; o1.w = c13;
        *(float4*)(hb + l * 32 + w4) = o0;
        *(float4*)(hb + (64 + l) * 32 + w4) = o1;
    } else {
        // out-proj: out[m] = T[m] @ W2 + b2  (T via LDS transpose, readlane W2)
        { float4 t4; t4.x = c00; t4.y = c01; t4.z = c02; t4.w = c03;
          *(float4*)&T_s[l * 32 + SWZg(l, w) * 4] = t4; }
        { float4 t4; t4.x = c10; t4.y = c11; t4.z = c12; t4.w = c13;
          *(float4*)&T_s[(64 + l) * 32 + SWZg(64 + l, w) * 4] = t4; }
        __syncthreads();
        float o00 = b2v.x, o01 = b2v.y, o10 = b2v.x, o11 = b2v.y;
#pragma unroll
        for (int k4 = 0; k4 < 8; ++k4) {
            float4 v0 = *(const float4*)&T_s[l * 32 + SWZg(l, k4) * 4];
            float4 v1 = *(const float4*)&T_s[(64 + l) * 32 + SWZg(64 + l, k4) * 4];
#define OPJ(j, VC0, VC1)                                                \
            { int k = k4 * 4 + (j);                                     \
              float e0 = rlane(w2r.x, k), e1 = rlane(w2r.y, k);         \
              o00 += (VC0) * e0; o01 += (VC0) * e1;                     \
              o10 += (VC1) * e0; o11 += (VC1) * e1; }
            OPJ(0, v0.x, v1.x)
            OPJ(1, v0.y, v1.y)
            OPJ(2, v0.z, v1.z)
            OPJ(3, v0.w, v1.w)
#undef OPJ
        }
        float* ob = out + ((size_t)(b * 64 + t)) * 2048;   // 128 rows * 16
        float2 r0; r0.x = o00; r0.y = o01;
        float2 r1; r1.x = o10; r1.y = o11;
        *(float2*)(ob + l * 16 + w * 2) = r0;
        *(float2*)(ob + (64 + l) * 16 + w * 2) = r1;
    }
}

// ---------------------------------------------------------------------------
extern "C" void kernel_launch(void* const* d_in, const int* in_sizes, int n_in,
                              void* d_out, int out_size, void* d_ws, size_t ws_size,
                              hipStream_t stream)
{
    const float* x   = (const float*)d_in[0];
    const float* At  = (const float*)d_in[1];
    const float* As  = (const float*)d_in[2];
    const float* s   = (const float*)d_in[3];
    const float* H   = (const float*)d_in[4];
    const float* W1  = (const float*)d_in[5];
    const float* b1  = (const float*)d_in[6];
    const float* W2  = (const float*)d_in[7];
    const float* b2  = (const float*)d_in[8];
    float* out = (float*)d_out;

    float* h1 = (float*)d_ws;              // [2][64][128][32]  524288 floats

    k_layer<true ><<<128, 512, 0, stream>>>(x,  At, As, s, H, W1, b1, W2, b2, h1, out);
    k_layer<false><<<128, 512, 0, stream>>>(h1, At, As, s, H, W1, b1, W2, b2, h1, out);
}

// Round 13
// 48.416 us; speedup vs baseline: 2.3344x; 2.3344x over previous
//
#include <hip/hip_runtime.h>

// GTCNN — 2-kernel fused-layer structure, round 13 (coalescing fix of r12).
// Block (b,t), 1024 threads, 128 blocks/kernel.
// Map A (stream/stores): thread tid owns 4 consecutive floats of each
//   4096-float row -> perfectly coalesced global access.
// Map B (project/spatial/filter): wave wv -> (fg = wv&7 f-chunk, mh = wv>>3);
//   lane l -> row m = mh*64+l. Weights via readlane register slices
//   (fg wave-uniform). As_s XOR-swizzled; stride-36 tiles = b128 8-phase floor.
//
// Math (verified r2-r12): mix = T h (stream over u); up = s1 h_t + s3 mix;
//   pp = s0 h_t + s2 mix; Ah = pp + S up; h' = tanh(Ah @ Hsum[l]).
// FIRST folds input projection by linearity:
//   T(xW1+b1)[t] = (Tx)[t] W1 + rowsum(At[t]) b1.
// LAST fuses output projection W2/b2.

#define SWZ(r, g) ((g) ^ ((r) & 7))

__device__ __forceinline__ float rlane(float v, int lane) {
    return __builtin_bit_cast(float, __builtin_amdgcn_readlane(__builtin_bit_cast(int, v), lane));
}

template<bool FIRST>
__global__ __launch_bounds__(1024) void k_layer(
    const float* __restrict__ src,   // FIRST ? x : h1   ([B][64][128*32])
    const float* __restrict__ At, const float* __restrict__ As,
    const float* __restrict__ s,  const float* __restrict__ H,
    const float* __restrict__ W1, const float* __restrict__ b1,
    const float* __restrict__ W2, const float* __restrict__ b2,
    float* __restrict__ h1, float* __restrict__ out)
{
    __shared__ float As_s[128 * 128];  // 64KB swizzled
    __shared__ float up_s[128 * 36];   // 18KB stride-36
    __shared__ float bufA[128 * 36];   // FIRST: xmix, then T(h1); !FIRST: pp
    __shared__ float bufB[128 * 36];   // FIRST: x_t;             !FIRST: T(out)
    __shared__ float Ah_s[128 * 36];   // 18KB
    // total 136KB -> 1 block/CU

    const int tid = threadIdx.x;
    const int b  = blockIdx.x >> 6, t = blockIdx.x & 63;
    const int wv = tid >> 6, l = tid & 63;
    const int fg = wv & 7, mh = wv >> 3;
    const int m  = mh * 64 + l;            // map B row
    const int nA = tid >> 3, fA = tid & 7; // map A row / col-group

    const float s0v = s[0], s1v = s[1], s2v = s[2], s3v = s[3];

    // ---- stage As [128][128] swizzled (coalesced read, conflict-free write) ----
#pragma unroll
    for (int i = 0; i < 4; ++i) {
        int p = tid + 1024 * i;
        int r = p >> 5, g = p & 31;
        float4 v = *(const float4*)(As + r * 128 + g * 4);
        *(float4*)&As_s[r * 128 + SWZ(r, g) * 4] = v;
    }

    // ---- temporal stream (map A, fully coalesced) ----
    const float* xb = src + (size_t)b * 262144;
    float atr = At[t * 64 + l];            // lane l: At[t][l]
    float4 mix; mix.x = mix.y = mix.z = mix.w = 0.f;
    float rs = 0.f;                        // rowsum At[t] (FIRST)
#pragma unroll 8
    for (int u = 0; u < 64; ++u) {
        float4 v = *(const float4*)(xb + u * 4096 + tid * 4);
        float a = rlane(atr, u);
        rs += a;
        mix.x += a * v.x; mix.y += a * v.y; mix.z += a * v.z; mix.w += a * v.w;
    }
    float4 hv = *(const float4*)(xb + t * 4096 + tid * 4);   // own row, L2-hot

    float4 up4, pp4;
    if (FIRST) {
        // stash raw mix and x_t for the k-reduction (map A write, 8-phase floor)
        *(float4*)&bufA[nA * 36 + fA * 4] = mix;   // xmix[n][k-chunk]
        *(float4*)&bufB[nA * 36 + fA * 4] = hv;    // x_t [n][k-chunk]
        __syncthreads();
        // projection in map B (thread (n=m, fg)); W1 via readlane slice
        float4 w1r = *(const float4*)(W1 + (l & 31) * 32 + fg * 4);
        float4 b1v = *(const float4*)(b1 + fg * 4);
        float h0 = b1v.x, h1_ = b1v.y, h2 = b1v.z, h3 = b1v.w;
        float q0 = rs * b1v.x, q1 = rs * b1v.y, q2 = rs * b1v.z, q3 = rs * b1v.w;
#pragma unroll
        for (int k4 = 0; k4 < 8; ++k4) {
            float4 xt4 = *(const float4*)&bufB[m * 36 + k4 * 4];
            float4 xm4 = *(const float4*)&bufA[m * 36 + k4 * 4];
#define PRJ(j, XT, XM)                                                  \
            { int k = k4 * 4 + (j);                                     \
              float c0 = rlane(w1r.x, k), c1 = rlane(w1r.y, k);         \
              float c2 = rlane(w1r.z, k), c3 = rlane(w1r.w, k);         \
              h0 += (XT) * c0; h1_ += (XT) * c1; h2 += (XT) * c2; h3 += (XT) * c3; \
              q0 += (XM) * c0; q1  += (XM) * c1; q2 += (XM) * c2; q3 += (XM) * c3; }
            PRJ(0, xt4.x, xm4.x)
            PRJ(1, xt4.y, xm4.y)
            PRJ(2, xt4.z, xm4.z)
            PRJ(3, xt4.w, xm4.w)
#undef PRJ
        }
        up4.x = s1v * h0 + s3v * q0;  up4.y = s1v * h1_ + s3v * q1;
        up4.z = s1v * h2 + s3v * q2;  up4.w = s1v * h3 + s3v * q3;
        pp4.x = s0v * h0 + s2v * q0;  pp4.y = s0v * h1_ + s2v * q1;
        pp4.z = s0v * h2 + s2v * q2;  pp4.w = s0v * h3 + s2v * q3;
        *(float4*)&up_s[m * 36 + fg * 4] = up4;      // pp stays in register
        __syncthreads();
    } else {
        // up/pp directly in map A; both round-trip LDS to reach map B
        up4.x = s1v * hv.x + s3v * mix.x;  up4.y = s1v * hv.y + s3v * mix.y;
        up4.z = s1v * hv.z + s3v * mix.z;  up4.w = s1v * hv.w + s3v * mix.w;
        pp4.x = s0v * hv.x + s2v * mix.x;  pp4.y = s0v * hv.y + s2v * mix.y;
        pp4.z = s0v * hv.z + s2v * mix.z;  pp4.w = s0v * hv.w + s2v * mix.w;
        *(float4*)&up_s[nA * 36 + fA * 4] = up4;
        *(float4*)&bufA[nA * 36 + fA * 4] = pp4;
        __syncthreads();
        pp4 = *(const float4*)&bufA[m * 36 + fg * 4];  // re-read in map B
    }

    // ---- spatial (map B): Ah[m] = pp[m] + sum_n As[m,n] up[n] ----
    float4 ua = *(const float4*)&up_s[l * 36 + fg * 4];          // lane l: up[l]
    float4 ub = *(const float4*)&up_s[(64 + l) * 36 + fg * 4];   // lane l: up[64+l]
    float4 ac = pp4;
#pragma unroll
    for (int n4 = 0; n4 < 32; ++n4) {
        float4 av = *(const float4*)&As_s[m * 128 + SWZ(m, n4) * 4];
#define SPJ(AV, NN)                                                     \
        { float u0, u1, u2, u3;                                         \
          if ((NN) < 64) { u0 = rlane(ua.x, (NN)); u1 = rlane(ua.y, (NN)); \
                           u2 = rlane(ua.z, (NN)); u3 = rlane(ua.w, (NN)); } \
          else { u0 = rlane(ub.x, (NN) - 64); u1 = rlane(ub.y, (NN) - 64); \
                 u2 = rlane(ub.z, (NN) - 64); u3 = rlane(ub.w, (NN) - 64); } \
          ac.x += (AV) * u0; ac.y += (AV) * u1; ac.z += (AV) * u2; ac.w += (AV) * u3; }
        SPJ(av.x, n4 * 4 + 0)
        SPJ(av.y, n4 * 4 + 1)
        SPJ(av.z, n4 * 4 + 2)
        SPJ(av.w, n4 * 4 + 3)
#undef SPJ
    }
    *(float4*)&Ah_s[m * 36 + fg * 4] = ac;

    // Hsum register slice (lane k = l&31 holds Hsum[k][fg-chunk])
    float4 hsr;
    {
        const float* Hl = H + (FIRST ? 0 : 4096) + (l & 31) * 32 + fg * 4;
        float4 q0 = *(const float4*)(Hl);
        float4 q1 = *(const float4*)(Hl + 1024);
        float4 q2 = *(const float4*)(Hl + 2048);
        float4 q3 = *(const float4*)(Hl + 3072);
        hsr.x = q0.x + q1.x + q2.x + q3.x;  hsr.y = q0.y + q1.y + q2.y + q3.y;
        hsr.z = q0.z + q1.z + q2.z + q3.z;  hsr.w = q0.w + q1.w + q2.w + q3.w;
    }
    __syncthreads();

    // ---- filter + tanh (map B) ----
    float4 c; c.x = c.y = c.z = c.w = 0.f;
#pragma unroll
    for (int k4 = 0; k4 < 8; ++k4) {
        float4 v = *(const float4*)&Ah_s[m * 36 + k4 * 4];
#define FLT(VV, KK)                                                     \
        { float d0 = rlane(hsr.x, (KK)), d1 = rlane(hsr.y, (KK));       \
          float d2 = rlane(hsr.z, (KK)), d3 = rlane(hsr.w, (KK));       \
          c.x += (VV) * d0; c.y += (VV) * d1; c.z += (VV) * d2; c.w += (VV) * d3; }
        FLT(v.x, k4 * 4 + 0)
        FLT(v.y, k4 * 4 + 1)
        FLT(v.z, k4 * 4 + 2)
        FLT(v.w, k4 * 4 + 3)
#undef FLT
    }
    c.x = tanhf(c.x); c.y = tanhf(c.y); c.z = tanhf(c.z); c.w = tanhf(c.w);

    if (FIRST) {
        // transpose through bufA (xmix dead since projection sync) -> coalesced h1 store
        *(float4*)&bufA[m * 36 + fg * 4] = c;
        __syncthreads();
        float4 o = *(const float4*)&bufA[nA * 36 + fA * 4];
        *(float4*)(h1 + ((size_t)(b * 64 + t)) * 4096 + tid * 4) = o;
    } else {
        // out-projection: T through bufB, W2 via readlane slice
        *(float4*)&bufB[m * 36 + fg * 4] = c;
        float2 w2r = *(const float2*)(W2 + (l & 31) * 16 + fg * 2);
        float2 b2v = *(const float2*)(b2 + fg * 2);
        __syncthreads();
        float o0 = b2v.x, o1 = b2v.y;
#pragma unroll
        for (int k4 = 0; k4 < 8; ++k4) {
            float4 v = *(const float4*)&bufB[m * 36 + k4 * 4];
#define OPJ(VV, KK)                                                     \
            { o0 += (VV) * rlane(w2r.x, (KK));                          \
              o1 += (VV) * rlane(w2r.y, (KK)); }
            OPJ(v.x, k4 * 4 + 0)
            OPJ(v.y, k4 * 4 + 1)
            OPJ(v.z, k4 * 4 + 2)
            OPJ(v.w, k4 * 4 + 3)
#undef OPJ
        }
        float2 o2; o2.x = o0; o2.y = o1;
        *(float2*)(out + ((size_t)(b * 64 + t)) * 2048 + m * 16 + fg * 2) = o2;
    }
}

// ---------------------------------------------------------------------------
extern "C" void kernel_launch(void* const* d_in, const int* in_sizes, int n_in,
                              void* d_out, int out_size, void* d_ws, size_t ws_size,
                              hipStream_t stream)
{
    const float* x   = (const float*)d_in[0];
    const float* At  = (const float*)d_in[1];
    const float* As  = (const float*)d_in[2];
    const float* s   = (const float*)d_in[3];
    const float* H   = (const float*)d_in[4];
    const float* W1  = (const float*)d_in[5];
    const float* b1  = (const float*)d_in[6];
    const float* W2  = (const float*)d_in[7];
    const float* b2  = (const float*)d_in[8];
    float* out = (float*)d_out;

    float* h1 = (float*)d_ws;              // [2][64][128][32]  524288 floats

    k_layer<true ><<<128, 1024, 0, stream>>>(x,  At, As, s, H, W1, b1, W2, b2, h1, out);
    k_layer<false><<<128, 1024, 0, stream>>>(h1, At, As, s, H, W1, b1, W2, b2, h1, out);
}

// Round 14
// 34.773 us; speedup vs baseline: 3.2502x; 1.3923x over previous
//
#include <hip/hip_runtime.h>

// GTCNN — 4-kernel chain (measured optimum: 6k=55.6, 4k=32.8, 2k-stream=48,
// 1k-persistent=84 us). Round-14: shrink the non-work term — temporal splits
// the f-dim (legal: temporal mixes only t; proj mixes k but xs stages all k)
// -> 512 blocks x 256 thr, 24KB LDS, 2+ blocks/CU (staging/compute overlap,
// half the per-block tail). Spatial cannot split f (filter mixes k) — keeps
// the proven r10 body. All bodies bit-identical math to r10 (absmax 4.88e-4).
//
// Math (verified r2-r13): w[t] = sum_u At[t,u] h[u]; up = s1 h + s3 w;
//   pp = s0 h + s2 w; Ah[m] = pp[m] + sum_n As[m,n] up[n];
//   h' = tanh(Ah @ Hsum[l]), Hsum[l] = sum_k H[l,k].
// Layouts: x[B][T*N][32]; up/pp[B][T][N][32]; hbuf[B][N][T][32] (n-major);
//   out[B][T*N][16].
// LDS discipline: lane-distinct tiles XOR-swizzled g' = g ^ (row&7) (b128
// conflict-ideal); wave-uniform operands via readlane register slices.

__device__ __forceinline__ int swz(int row, int g) { return g ^ (row & 7); }

__device__ __forceinline__ float rlane(float v, int lane) {
    return __builtin_bit_cast(float, __builtin_amdgcn_readlane(__builtin_bit_cast(int, v), lane));
}

// ---------------------------------------------------------------------------
// Temporal kernel. grid = B*N*2 = 512 blocks, 256 threads (4 waves).
// blk -> (b, n, fh f-half); wave wv -> f-chunk fg = fh*4+wv (4 floats at fg*4);
// lane lt = t AND slice slot u (lane u holds h[u][chunk] in regs).
// ---------------------------------------------------------------------------
template<bool PROJ>
__global__ __launch_bounds__(256) void k_temporal(
    const float* __restrict__ src,     // PROJ ? x : hbuf (n-major)
    const float* __restrict__ At,
    const float* __restrict__ W1, const float* __restrict__ b1,
    const float* __restrict__ s,
    float* __restrict__ up, float* __restrict__ pp)
{
    __shared__ float At_s[64 * 64];   // 16KB swizzled (b128 lane-distinct)
    __shared__ float xs  [64 * 32];   //  8KB swizzled (PROJ only)

    const int tid = threadIdx.x;
    const int blk = blockIdx.x;
    const int b   = blk >> 8;
    const int n   = (blk >> 1) & 127;
    const int fh  = blk & 1;
    const int wv  = tid >> 6;
    const int lt  = tid & 63;
    const int c   = (fh * 4 + wv) * 4;         // f-chunk byte offset /4

    const float s0v = s[0], s1v = s[1], s2v = s[2], s3v = s[3];

    // stage At [64][64] -> swizzled groups (16 scalar writes/thread)
#pragma unroll
    for (int i = 0; i < 16; ++i) {
        int p = tid + 256 * i;
        int r = p >> 6, cc = p & 63;
        At_s[r * 64 + (swz(r, cc >> 2) << 2) + (cc & 3)] = At[p];
    }

    float h0, h1, h2, h3;
    if (PROJ) {
        // stage x rows (all 32 k needed) -> xs swizzled (2 float4/thread)
#pragma unroll
        for (int i = 0; i < 2; ++i) {
            int q = tid + 256 * i;
            int tt = q >> 3, c4 = q & 7;
            float4 v = *(const float4*)(src + ((size_t)(b * 8192 + tt * 128 + n)) * 32 + c4 * 4);
            *(float4*)&xs[tt * 32 + (swz(tt, c4) << 2)] = v;
        }
        // W1 slice: lane l holds W1[k=l&31][chunk]
        float4 w1r = *(const float4*)(W1 + (lt & 31) * 32 + c);
        float4 bv  = *(const float4*)(b1 + c);
        __syncthreads();
        h0 = bv.x; h1 = bv.y; h2 = bv.z; h3 = bv.w;
#pragma unroll
        for (int k4 = 0; k4 < 8; ++k4) {
            float4 xv = *(const float4*)&xs[lt * 32 + (swz(lt, k4) << 2)];
#define PROJSTEP(a, k)                                   \
            h0 += (a) * rlane(w1r.x, (k));               \
            h1 += (a) * rlane(w1r.y, (k));               \
            h2 += (a) * rlane(w1r.z, (k));               \
            h3 += (a) * rlane(w1r.w, (k));
            PROJSTEP(xv.x, k4 * 4 + 0)
            PROJSTEP(xv.y, k4 * 4 + 1)
            PROJSTEP(xv.z, k4 * 4 + 2)
            PROJSTEP(xv.w, k4 * 4 + 3)
#undef PROJSTEP
        }
        // lane t now holds h[t][chunk] == slice slot the mix needs (u = lane)
    } else {
        float4 hv = *(const float4*)(src + (((size_t)(b * 128 + n)) * 64 + lt) * 32 + c);
        h0 = hv.x; h1 = hv.y; h2 = hv.z; h3 = hv.w;
        __syncthreads();                 // At_s ready
    }

    // temporal mix: At b128 lane-distinct + readlane h (lane u)
    float w0 = 0.f, w1 = 0.f, w2 = 0.f, w3 = 0.f;
#pragma unroll
    for (int u4 = 0; u4 < 16; ++u4) {
        float4 av = *(const float4*)&At_s[lt * 64 + (swz(lt, u4) << 2)];
#define MIXSTEP(a, u)                                    \
        w0 += (a) * rlane(h0, (u));                      \
        w1 += (a) * rlane(h1, (u));                      \
        w2 += (a) * rlane(h2, (u));                      \
        w3 += (a) * rlane(h3, (u));
        MIXSTEP(av.x, u4 * 4 + 0)
        MIXSTEP(av.y, u4 * 4 + 1)
        MIXSTEP(av.z, u4 * 4 + 2)
        MIXSTEP(av.w, u4 * 4 + 3)
#undef MIXSTEP
    }
    float4 uo, po;
    uo.x = s1v * h0 + s3v * w0;  po.x = s0v * h0 + s2v * w0;
    uo.y = s1v * h1 + s3v * w1;  po.y = s0v * h1 + s2v * w1;
    uo.z = s1v * h2 + s3v * w2;  po.z = s0v * h2 + s2v * w2;
    uo.w = s1v * h3 + s3v * w3;  po.w = s0v * h3 + s2v * w3;
    size_t base = ((size_t)((b * 64 + lt) * 128 + n)) * 32 + c;
    *(float4*)(up + base) = uo;
    *(float4*)(pp + base) = po;
}

// ---------------------------------------------------------------------------
// Spatial kernel (r10 body, proven). grid = B*T*2 = 256, 512 threads.
// wave fg = tid>>6, lane m = tid&63 (local row of half mh; also slice slot:
// lane l holds up[n=2l..2l+1][fg-chunk], Hsum[k=l&31][fg-chunk]).
// ---------------------------------------------------------------------------
template<bool LAST>
__global__ __launch_bounds__(512) void k_spatial(
    const float* __restrict__ up, const float* __restrict__ pp,
    const float* __restrict__ As, const float* __restrict__ H, int layer,
    const float* __restrict__ W2, const float* __restrict__ b2,
    float* __restrict__ hout, float* __restrict__ out)
{
    __shared__ float As_s[64 * 128];  // 32KB swizzled (b128 lane-distinct)
    __shared__ float Ah_s[64 * 32];   //  8KB swizzled
    __shared__ float T_s [64 * 32];   //  8KB swizzled (LAST only)

    const int tid = threadIdx.x;
    const int b   = blockIdx.x >> 7;
    const int t   = (blockIdx.x >> 1) & 63;
    const int mh  = blockIdx.x & 1;
    const int fg  = tid >> 6;
    const int m   = tid & 63;

    // stage As half-tile [64][128] swizzled
#pragma unroll
    for (int i = 0; i < 4; ++i) {
        int p = tid + 512 * i;
        int r = p >> 5, g = p & 31;
        float4 v = *(const float4*)(As + ((size_t)(mh * 64 + r)) * 128 + g * 4);
        *(float4*)&As_s[r * 128 + (swz(r, g) << 2)] = v;
    }
    // up register slice: lane l holds n=2l (ua) and n=2l+1 (ub)
    const float* urow = up + ((size_t)(b * 64 + t)) * 4096;
    float4 ua = *(const float4*)(urow + (2 * m)     * 32 + fg * 4);
    float4 ub = *(const float4*)(urow + (2 * m + 1) * 32 + fg * 4);
    // Hsum register slice: lane l holds k = l&31
    float4 hsr;
    {
        const float* Hl = H + layer * 4096 + (m & 31) * 32 + fg * 4;
        float4 q0 = *(const float4*)(Hl);
        float4 q1 = *(const float4*)(Hl + 1024);
        float4 q2 = *(const float4*)(Hl + 2048);
        float4 q3 = *(const float4*)(Hl + 3072);
        hsr.x = q0.x + q1.x + q2.x + q3.x;
        hsr.y = q0.y + q1.y + q2.y + q3.y;
        hsr.z = q0.z + q1.z + q2.z + q3.z;
        hsr.w = q0.w + q1.w + q2.w + q3.w;
    }
    float2 w2r, b2v;
    if (LAST) {
        w2r = *(const float2*)(W2 + (m & 31) * 16 + fg * 2);
        b2v = *(const float2*)(b2 + fg * 2);
    }
    // acc init from pp
    float4 pv = *(const float4*)(pp + ((size_t)((b * 64 + t) * 128 + mh * 64 + m)) * 32 + fg * 4);
    float a0 = pv.x, a1 = pv.y, a2 = pv.z, a3 = pv.w;
    __syncthreads();

    // spatial mix: As b128 lane-distinct swizzled + readlane up
#pragma unroll
    for (int n4 = 0; n4 < 32; ++n4) {
        float4 av = *(const float4*)&As_s[m * 128 + (swz(m, n4) << 2)];
#define SPSTEP(a, reg, ln)                               \
        a0 += (a) * rlane(reg.x, (ln));                  \
        a1 += (a) * rlane(reg.y, (ln));                  \
        a2 += (a) * rlane(reg.z, (ln));                  \
        a3 += (a) * rlane(reg.w, (ln));
        SPSTEP(av.x, ua, 2 * n4)          // n = 4*n4
        SPSTEP(av.y, ub, 2 * n4)          // n = 4*n4+1
        SPSTEP(av.z, ua, 2 * n4 + 1)      // n = 4*n4+2
        SPSTEP(av.w, ub, 2 * n4 + 1)      // n = 4*n4+3
#undef SPSTEP
    }
    {
        float4 t4; t4.x = a0; t4.y = a1; t4.z = a2; t4.w = a3;
        *(float4*)&Ah_s[m * 32 + (swz(m, fg) << 2)] = t4;
    }
    __syncthreads();

    // graph filter + tanh: Ah b128 lane-distinct + readlane Hsum
    float c0 = 0.f, c1 = 0.f, c2 = 0.f, c3 = 0.f;
#pragma unroll
    for (int k4 = 0; k4 < 8; ++k4) {
        float4 av = *(const float4*)&Ah_s[m * 32 + (swz(m, k4) << 2)];
#define FSTEP(a, k)                                      \
        c0 += (a) * rlane(hsr.x, (k));                   \
        c1 += (a) * rlane(hsr.y, (k));                   \
        c2 += (a) * rlane(hsr.z, (k));                   \
        c3 += (a) * rlane(hsr.w, (k));
        FSTEP(av.x, k4 * 4 + 0)
        FSTEP(av.y, k4 * 4 + 1)
        FSTEP(av.z, k4 * 4 + 2)
        FSTEP(av.w, k4 * 4 + 3)
#undef FSTEP
    }
    c0 = tanhf(c0); c1 = tanhf(c1); c2 = tanhf(c2); c3 = tanhf(c3);

    if (!LAST) {
        float4 o; o.x = c0; o.y = c1; o.z = c2; o.w = c3;
        // h stored n-major: [b][nglob][t][f]
        *(float4*)(hout + (((size_t)(b * 128 + mh * 64 + m)) * 64 + t) * 32 + fg * 4) = o;
    } else {
        float4 t4; t4.x = c0; t4.y = c1; t4.z = c2; t4.w = c3;
        *(float4*)&T_s[m * 32 + (swz(m, fg) << 2)] = t4;
        __syncthreads();
        // fused output projection: wave fg covers fo = {fg*2, fg*2+1}
        float o0 = b2v.x, o1 = b2v.y;
#pragma unroll
        for (int k4 = 0; k4 < 8; ++k4) {
            float4 tv = *(const float4*)&T_s[m * 32 + (swz(m, k4) << 2)];
#define OSTEP(a, k)                                      \
            o0 += (a) * rlane(w2r.x, (k));               \
            o1 += (a) * rlane(w2r.y, (k));
            OSTEP(tv.x, k4 * 4 + 0)
            OSTEP(tv.y, k4 * 4 + 1)
            OSTEP(tv.z, k4 * 4 + 2)
            OSTEP(tv.w, k4 * 4 + 3)
#undef OSTEP
        }
        float2 o2; o2.x = o0; o2.y = o1;
        *(float2*)(out + ((size_t)((b * 64 + t) * 128 + mh * 64 + m)) * 16 + fg * 2) = o2;
    }
}

// ---------------------------------------------------------------------------
extern "C" void kernel_launch(void* const* d_in, const int* in_sizes, int n_in,
                              void* d_out, int out_size, void* d_ws, size_t ws_size,
                              hipStream_t stream)
{
    const float* x   = (const float*)d_in[0];
    const float* At  = (const float*)d_in[1];
    const float* As  = (const float*)d_in[2];
    const float* s   = (const float*)d_in[3];
    const float* H   = (const float*)d_in[4];
    const float* W1  = (const float*)d_in[5];
    const float* b1  = (const float*)d_in[6];
    const float* W2  = (const float*)d_in[7];
    const float* b2  = (const float*)d_in[8];
    float* out = (float*)d_out;

    float* up   = (float*)d_ws;            // [2][64][128][32]  524288 floats
    float* pp   = up + 524288;             // same layout
    float* hbuf = pp + 524288;             // [2][128][64][32]  n-major

    k_temporal<true ><<<512, 256, 0, stream>>>(x,    At, W1, b1, s, up, pp);
    k_spatial <false><<<256, 512, 0, stream>>>(up, pp, As, H, 0, W2, b2, hbuf, out);
    k_temporal<false><<<512, 256, 0, stream>>>(hbuf, At, W1, b1, s, up, pp);
    k_spatial <true ><<<256, 512, 0, stream>>>(up, pp, As, H, 1, W2, b2, hbuf, out);
}

// Round 15
// 32.752 us; speedup vs baseline: 3.4508x; 1.0617x over previous
//
#include <hip/hip_runtime.h>

// GTCNN — FINAL: 4-kernel chain, exact round-9 configuration (measured optimum
// 32.8us across 13 structural variants; see round-15 analysis).
// Structure is provably minimal: 4 alternating all-to-alls (t,n,t,n) with
// projections fused into stages 1 and 4; kernel boundary = cheapest device-
// wide ordering point (~3us vs ~25us software grid barrier, r8).
//
// Math (verified r2-r14): Adj = s0 I + s1 (I⊗As) + s2 (At⊗I) + s3 (At⊗As)
//   per layer: w[t] = sum_u At[t,u] h[u]  (temporal, per (b,n) column)
//              up = s1 h + s3 w ; pp = s0 h + s2 w
//              Ah[m] = pp[m] + sum_n As[m,n] up[n]  (spatial, per (b,t))
//              h' = tanh(Ah @ Hsum[l]),  Hsum[l] = sum_k H[l,k]
// Kernels: T0 = proj(x@W1+b1)+temporal ; S0 = spatial+filter -> hbuf (n-major)
//          T1 = temporal ; S1 = spatial+filter+out-proj(W2,b2)
//
// LDS discipline (HW-proven r6-r14): lane-distinct tiles XOR group swizzle
// g' = g ^ (row&7) (b128 conflict-ideal); wave-uniform operands -> linear LDS
// broadcast (free) — LDS-broadcast beat both global-uniform (r5) and
// stride-256B register slices (r10/r14) for the spatial up operand.
// Layouts: x[B][T*N][32]; up/pp[B][T][N][32]; hbuf[B][N][T][32] (n-major);
//          out[B][T*N][16].

__device__ __forceinline__ int swz(int row, int g) { return g ^ (row & 7); }

// ---------------------------------------------------------------------------
// Temporal kernel. grid = B*N = 256, 512 threads.
// wave fg = tid>>6 (4-float f-chunk), lane lt = tid&63 (time step).
// ---------------------------------------------------------------------------
template<bool PROJ>
__global__ __launch_bounds__(512) void k_temporal(
    const float* __restrict__ src,     // PROJ ? x : hbuf (n-major)
    const float* __restrict__ At,
    const float* __restrict__ W1, const float* __restrict__ b1,
    const float* __restrict__ s,
    float* __restrict__ up, float* __restrict__ pp)
{
    __shared__ float At_s[64 * 64];   // swizzled, b128 reads (4 u per DS op)
    __shared__ float xs  [64 * 32];   // swizzled (PROJ only)
    __shared__ float hls [64 * 32];   // swizzled writes, broadcast reads
    __shared__ float W1s [1024];      // linear (broadcast reads, PROJ only)

    const int tid = threadIdx.x;
    const int b   = blockIdx.x >> 7;
    const int n   = blockIdx.x & 127;
    const int fg  = tid >> 6;
    const int lt  = tid & 63;

    const float s0v = s[0], s1v = s[1], s2v = s[2], s3v = s[3];

    // stage At [64][64] -> swizzled groups (scalar writes, 2-way = free)
#pragma unroll
    for (int i = 0; i < 8; ++i) {
        int p = tid + 512 * i;
        int r = p >> 6, c = p & 63;
        At_s[r * 64 + (swz(r, c >> 2) << 2) + (c & 3)] = At[p];
    }

    if (PROJ) {
        // stage x rows x[b, t*128+n, :] -> xs (swizzled)
        {
            int tt = tid >> 3, c4 = tid & 7;
            float4 v = *(const float4*)(src + ((size_t)(b * 8192 + tt * 128 + n)) * 32 + c4 * 4);
            *(float4*)&xs[tt * 32 + (swz(tt, c4) << 2)] = v;
        }
        if (tid < 256) ((float4*)W1s)[tid] = ((const float4*)W1)[tid];
        __syncthreads();
        // h = x @ W1 + b1  (xs b128 lane-distinct; W1s broadcast)
        float4 bv = *(const float4*)(b1 + fg * 4);
        float h0 = bv.x, h1 = bv.y, h2 = bv.z, h3 = bv.w;
#pragma unroll
        for (int k4 = 0; k4 < 8; ++k4) {
            float4 xv = *(const float4*)&xs[lt * 32 + (swz(lt, k4) << 2)];
            float4 w0 = *(const float4*)&W1s[(k4 * 4 + 0) * 32 + fg * 4];
            float4 w1 = *(const float4*)&W1s[(k4 * 4 + 1) * 32 + fg * 4];
            float4 w2 = *(const float4*)&W1s[(k4 * 4 + 2) * 32 + fg * 4];
            float4 w3 = *(const float4*)&W1s[(k4 * 4 + 3) * 32 + fg * 4];
            h0 += xv.x * w0.x + xv.y * w1.x + xv.z * w2.x + xv.w * w3.x;
            h1 += xv.x * w0.y + xv.y * w1.y + xv.z * w2.y + xv.w * w3.y;
            h2 += xv.x * w0.z + xv.y * w1.z + xv.z * w2.z + xv.w * w3.z;
            h3 += xv.x * w0.w + xv.y * w1.w + xv.z * w2.w + xv.w * w3.w;
        }
        float4 hv; hv.x = h0; hv.y = h1; hv.z = h2; hv.w = h3;
        *(float4*)&hls[lt * 32 + (swz(lt, fg) << 2)] = hv;
        __syncthreads();
    } else {
        // stage h row (b,n): contiguous 8KB -> hls (swizzled)
        {
            int tt = tid >> 3, c4 = tid & 7;
            float4 v = *(const float4*)(src + ((size_t)(b * 128 + n)) * 2048 + tt * 32 + c4 * 4);
            *(float4*)&hls[tt * 32 + (swz(tt, c4) << 2)] = v;
        }
        __syncthreads();
    }

    // temporal mix: At b128 lane-distinct (1 DS / 4 u's) + 4 broadcast h reads
    float4 hv = *(const float4*)&hls[lt * 32 + (swz(lt, fg) << 2)];
    float w0 = 0.f, w1 = 0.f, w2 = 0.f, w3 = 0.f;
#pragma unroll
    for (int u4 = 0; u4 < 16; ++u4) {
        float4 av = *(const float4*)&At_s[lt * 64 + (swz(lt, u4) << 2)];
        float4 g0 = *(const float4*)&hls[(u4 * 4 + 0) * 32 + (swz(u4 * 4 + 0, fg) << 2)];
        float4 g1 = *(const float4*)&hls[(u4 * 4 + 1) * 32 + (swz(u4 * 4 + 1, fg) << 2)];
        float4 g2 = *(const float4*)&hls[(u4 * 4 + 2) * 32 + (swz(u4 * 4 + 2, fg) << 2)];
        float4 g3 = *(const float4*)&hls[(u4 * 4 + 3) * 32 + (swz(u4 * 4 + 3, fg) << 2)];
        w0 += av.x * g0.x + av.y * g1.x + av.z * g2.x + av.w * g3.x;
        w1 += av.x * g0.y + av.y * g1.y + av.z * g2.y + av.w * g3.y;
        w2 += av.x * g0.z + av.y * g1.z + av.z * g2.z + av.w * g3.z;
        w3 += av.x * g0.w + av.y * g1.w + av.z * g2.w + av.w * g3.w;
    }
    float4 uo, po;
    uo.x = s1v * hv.x + s3v * w0;  po.x = s0v * hv.x + s2v * w0;
    uo.y = s1v * hv.y + s3v * w1;  po.y = s0v * hv.y + s2v * w1;
    uo.z = s1v * hv.z + s3v * w2;  po.z = s0v * hv.z + s2v * w2;
    uo.w = s1v * hv.w + s3v * w3;  po.w = s0v * hv.w + s2v * w3;
    size_t base = ((size_t)((b * 64 + lt) * 128 + n)) * 32 + fg * 4;
    *(float4*)(up + base) = uo;
    *(float4*)(pp + base) = po;
}

// ---------------------------------------------------------------------------
// Spatial kernel. grid = B*T*2 = 256, 512 threads.
// wave fg = tid>>6, lane m = tid&63 (local row of half mh).
// ---------------------------------------------------------------------------
template<bool LAST>
__global__ __launch_bounds__(512) void k_spatial(
    const float* __restrict__ up, const float* __restrict__ pp,
    const float* __restrict__ As, const float* __restrict__ H, int layer,
    const float* __restrict__ W2, const float* __restrict__ b2,
    float* __restrict__ hout, float* __restrict__ out)
{
    __shared__ float As_s[64 * 128];  // 32KB swizzled (b128 lane-distinct)
    __shared__ float up_s[128 * 32];  // 16KB linear (broadcast reads)
    __shared__ float Ah_s[64 * 32];   //  8KB swizzled
    __shared__ float T_s [64 * 32];   //  8KB swizzled (LAST only)
    __shared__ float Hs  [1024];      //  4KB linear (broadcast)
    __shared__ float W2s [512];       //  2KB linear (broadcast, LAST only)

    const int tid = threadIdx.x;
    const int b   = blockIdx.x >> 7;
    const int t   = (blockIdx.x >> 1) & 63;
    const int mh  = blockIdx.x & 1;
    const int fg  = tid >> 6;
    const int m   = tid & 63;

    // stage As half-tile [64][128] swizzled
#pragma unroll
    for (int i = 0; i < 4; ++i) {
        int p = tid + 512 * i;
        int r = p >> 5, g = p & 31;
        float4 v = *(const float4*)(As + ((size_t)(mh * 64 + r)) * 128 + g * 4);
        *(float4*)&As_s[r * 128 + (swz(r, g) << 2)] = v;
    }
    // stage up tile [128][32] linear (coalesced)
    {
        const float* usrc = up + ((size_t)(b * 64 + t)) * 4096;
        ((float4*)up_s)[tid]       = ((const float4*)usrc)[tid];
        ((float4*)up_s)[tid + 512] = ((const float4*)usrc)[tid + 512];
    }
    // Hsum for this layer
    {
        const float* Hl = H + layer * 4096;
#pragma unroll
        for (int i = 0; i < 2; ++i) {
            int p = tid + 512 * i;
            Hs[p] = Hl[p] + Hl[1024 + p] + Hl[2048 + p] + Hl[3072 + p];
        }
    }
    if (LAST && tid < 128) ((float4*)W2s)[tid] = ((const float4*)W2)[tid];
    // acc init from pp (lane-distinct; overlaps staging)
    float4 pv = *(const float4*)(pp + ((size_t)((b * 64 + t) * 128 + mh * 64 + m)) * 32 + fg * 4);
    float a0 = pv.x, a1 = pv.y, a2 = pv.z, a3 = pv.w;
    __syncthreads();

    // spatial mix: As b128 lane-distinct swizzled + 4 broadcast up reads
#pragma unroll 8
    for (int n4 = 0; n4 < 32; ++n4) {
        float4 av = *(const float4*)&As_s[m * 128 + (swz(m, n4) << 2)];
        float4 u0 = *(const float4*)&up_s[(n4 * 4 + 0) * 32 + fg * 4];
        float4 u1 = *(const float4*)&up_s[(n4 * 4 + 1) * 32 + fg * 4];
        float4 u2 = *(const float4*)&up_s[(n4 * 4 + 2) * 32 + fg * 4];
        float4 u3 = *(const float4*)&up_s[(n4 * 4 + 3) * 32 + fg * 4];
        a0 += av.x * u0.x + av.y * u1.x + av.z * u2.x + av.w * u3.x;
        a1 += av.x * u0.y + av.y * u1.y + av.z * u2.y + av.w * u3.y;
        a2 += av.x * u0.z + av.y * u1.z + av.z * u2.z + av.w * u3.z;
        a3 += av.x * u0.w + av.y * u1.w + av.z * u2.w + av.w * u3.w;
    }
    {
        float4 t4; t4.x = a0; t4.y = a1; t4.z = a2; t4.w = a3;
        *(float4*)&Ah_s[m * 32 + (swz(m, fg) << 2)] = t4;
    }
    __syncthreads();

    // graph filter + tanh: Ah b128 lane-distinct + Hs broadcast
    float c0 = 0.f, c1 = 0.f, c2 = 0.f, c3 = 0.f;
#pragma unroll
    for (int k4 = 0; k4 < 8; ++k4) {
        float4 av = *(const float4*)&Ah_s[m * 32 + (swz(m, k4) << 2)];
        float4 q0 = *(const float4*)&Hs[(k4 * 4 + 0) * 32 + fg * 4];
        float4 q1 = *(const float4*)&Hs[(k4 * 4 + 1) * 32 + fg * 4];
        float4 q2 = *(const float4*)&Hs[(k4 * 4 + 2) * 32 + fg * 4];
        float4 q3 = *(const float4*)&Hs[(k4 * 4 + 3) * 32 + fg * 4];
        c0 += av.x * q0.x + av.y * q1.x + av.z * q2.x + av.w * q3.x;
        c1 += av.x * q0.y + av.y * q1.y + av.z * q2.y + av.w * q3.y;
        c2 += av.x * q0.z + av.y * q1.z + av.z * q2.z + av.w * q3.z;
        c3 += av.x * q0.w + av.y * q1.w + av.z * q2.w + av.w * q3.w;
    }
    c0 = tanhf(c0); c1 = tanhf(c1); c2 = tanhf(c2); c3 = tanhf(c3);

    if (!LAST) {
        float4 o; o.x = c0; o.y = c1; o.z = c2; o.w = c3;
        // h stored n-major: [b][nglob][t][f]
        *(float4*)(hout + (((size_t)(b * 128 + mh * 64 + m)) * 64 + t) * 32 + fg * 4) = o;
    } else {
        float4 t4; t4.x = c0; t4.y = c1; t4.z = c2; t4.w = c3;
        *(float4*)&T_s[m * 32 + (swz(m, fg) << 2)] = t4;
        __syncthreads();
        // fused output projection: wave fg covers fo = {fg*2, fg*2+1}
        const int fo = fg * 2;
        float o0 = b2[fo], o1 = b2[fo + 1];
#pragma unroll
        for (int k4 = 0; k4 < 8; ++k4) {
            float4 tv = *(const float4*)&T_s[m * 32 + (swz(m, k4) << 2)];
            float2 v0 = *(const float2*)&W2s[(k4 * 4 + 0) * 16 + fo];
            float2 v1 = *(const float2*)&W2s[(k4 * 4 + 1) * 16 + fo];
            float2 v2 = *(const float2*)&W2s[(k4 * 4 + 2) * 16 + fo];
            float2 v3 = *(const float2*)&W2s[(k4 * 4 + 3) * 16 + fo];
            o0 += tv.x * v0.x + tv.y * v1.x + tv.z * v2.x + tv.w * v3.x;
            o1 += tv.x * v0.y + tv.y * v1.y + tv.z * v2.y + tv.w * v3.y;
        }
        float2 o2; o2.x = o0; o2.y = o1;
        *(float2*)(out + ((size_t)((b * 64 + t) * 128 + mh * 64 + m)) * 16 + fo) = o2;
    }
}

// ---------------------------------------------------------------------------
extern "C" void kernel_launch(void* const* d_in, const int* in_sizes, int n_in,
                              void* d_out, int out_size, void* d_ws, size_t ws_size,
                              hipStream_t stream)
{
    const float* x   = (const float*)d_in[0];
    const float* At  = (const float*)d_in[1];
    const float* As  = (const float*)d_in[2];
    const float* s   = (const float*)d_in[3];
    const float* H   = (const float*)d_in[4];
    const float* W1  = (const float*)d_in[5];
    const float* b1  = (const float*)d_in[6];
    const float* W2  = (const float*)d_in[7];
    const float* b2  = (const float*)d_in[8];
    float* out = (float*)d_out;

    float* up   = (float*)d_ws;            // [2][64][128][32]  524288 floats
    float* pp   = up + 524288;             // same layout
    float* hbuf = pp + 524288;             // [2][128][64][32]  n-major

    k_temporal<true ><<<256, 512, 0, stream>>>(x,    At, W1, b1, s, up, pp);
    k_spatial <false><<<256, 512, 0, stream>>>(up, pp, As, H, 0, W2, b2, hbuf, out);
    k_temporal<false><<<256, 512, 0, stream>>>(hbuf, At, W1, b1, s, up, pp);
    k_spatial <true ><<<256, 512, 0, stream>>>(up, pp, As, H, 1, W2, b2, hbuf, out);
}